// Round 5
// baseline (32247.955 us; speedup 1.0000x reference)
//
#include <hip/hip_runtime.h>

// Decoder GRU, B=128 T=512 X=64 H=256, skip=4 (runtime).
// Round 5: the bound is the per-CU weight stream from L2 (R4: 1 MB/step/CU at
// 47 B/cyc ~ 78% of the ~60 B/cyc per-CU L2 rate).  Halve the bytes: weights
// are converted to bf16 (RNE) and k8-major-transposed by a prep kernel; the
// main kernel streams uint4 = 8 bf16 weights per 16B load and unpacks to fp32
// (1 VALU op/weight) with fp32 FMA accumulate.  Activations/state stay fp32.
// 128 WGs x 1024 thr (16 waves, 4/SIMD), 1 batch per WG, all state in LDS,
// zero inter-WG communication.  LDS padded >80 KB so 2 WGs never share a CU
// (would double the per-CU stream).
constexpr int T_ = 512;
constexpr int X_ = 64;
constexpr int H_ = 256;
constexpr int NWG = 128;  // 1 batch per WG
constexpr int NT = 1024;  // 16 waves
constexpr int RS = 16;    // ring slots; lookback 2*skip, OK for skip <= 7

// bf16 weight store in d_ws, uint4 = 8 k-consecutive bf16 for one column.
constexpr int U4_HH = 32 * 768;   // k8 x (3H cols)  -> 384 KB
constexpr int U4_IH = 8 * 768;    //                  ->  96 KB
constexpr int U4_OUT = 32 * 64;   //                  ->  32 KB
constexpr int U4_TOTAL = U4_HH + U4_IH + U4_OUT;  // 32768 entries = 512 KB

__device__ __forceinline__ float sigmoid_f(float x) {
  float e = __expf(fminf(-x, 80.f));
  return 1.f / (1.f + e);
}
__device__ __forceinline__ float tanh_f(float x) {
  float e = __expf(fminf(-2.f * x, 80.f));
  return (1.f - e) / (1.f + e);
}

// round-to-nearest-even fp32 -> bf16, pack two into a uint (a=low, b=high)
__device__ __forceinline__ unsigned bfpair(float a, float b) {
  unsigned ua = __float_as_uint(a);
  ua = (ua + 0x7FFFu + ((ua >> 16) & 1u)) >> 16;
  unsigned ub = __float_as_uint(b);
  ub = (ub + 0x7FFFu + ((ub >> 16) & 1u)) & 0xFFFF0000u;
  return ub | ua;
}

// 8 bf16 weights (uint4) dotted with 8 fp32 activations (two float4)
__device__ __forceinline__ float dot8(uint4 w, float4 a, float4 b, float acc) {
  acc = fmaf(a.x, __uint_as_float(w.x << 16), acc);
  acc = fmaf(a.y, __uint_as_float(w.x & 0xFFFF0000u), acc);
  acc = fmaf(a.z, __uint_as_float(w.y << 16), acc);
  acc = fmaf(a.w, __uint_as_float(w.y & 0xFFFF0000u), acc);
  acc = fmaf(b.x, __uint_as_float(w.z << 16), acc);
  acc = fmaf(b.y, __uint_as_float(w.z & 0xFFFF0000u), acc);
  acc = fmaf(b.z, __uint_as_float(w.w << 16), acc);
  acc = fmaf(b.w, __uint_as_float(w.w & 0xFFFF0000u), acc);
  return acc;
}

// One-time: fp32 weights -> bf16, k8-major layout T[k8*cols + col].
__global__ void prep_kernel(const float* __restrict__ Wih,
                            const float* __restrict__ Whh,
                            const float* __restrict__ Wout,
                            uint4* __restrict__ T) {
  int id = blockIdx.x * 256 + threadIdx.x;
  const float* s;
  if (id < U4_HH) {
    int k8 = id / 768, cg = id - k8 * 768;
    s = Whh + (size_t)cg * H_ + k8 * 8;
  } else if (id < U4_HH + U4_IH) {
    int j = id - U4_HH;
    int k8 = j / 768, cg = j - k8 * 768;
    s = Wih + (size_t)cg * X_ + k8 * 8;
  } else if (id < U4_TOTAL) {
    int j = id - U4_HH - U4_IH;
    int k8 = j >> 6, c = j & 63;
    s = Wout + (size_t)c * H_ + k8 * 8;
  } else {
    return;
  }
  uint4 v;
  v.x = bfpair(s[0], s[1]);
  v.y = bfpair(s[2], s[3]);
  v.z = bfpair(s[4], s[5]);
  v.w = bfpair(s[6], s[7]);
  T[id] = v;
}

struct Tab {
  float m0, m1;
  bool gz, pz;
  int gi, pi;
};
__device__ __forceinline__ Tab tables(int i, int skip,
                                      const int* __restrict__ mask0,
                                      const int* __restrict__ mask1) {
  Tab tb;
  tb.m0 = (float)mask0[i];
  tb.m1 = (float)mask1[i];
  int pg = (i < skip) ? 2 * i : i - skip;
  tb.gz = pg < skip;
  int gi = pg - skip;
  if (gi < 0) gi = 0;
  if (gi >= i) tb.gz = true;  // unwritten slot == reference's zero init
  tb.gi = gi;
  int pp_ = (i < skip) ? 2 * i + 1 : i - skip;
  tb.pz = pp_ < skip;
  int pi = pp_ - skip;
  if (pi < 0) pi = 0;
  tb.pi = pi;
  return tb;
}

extern __shared__ float dyn_pad[];  // occupancy guard (see launch)

__global__ __launch_bounds__(NT, 1) void decoder_kernel(
    const float* __restrict__ h_enc, const float* __restrict__ b_ih,
    const float* __restrict__ b_hh, const float* __restrict__ b_out,
    const int* __restrict__ mask0, const int* __restrict__ mask1,
    const int* __restrict__ skipp, const uint4* __restrict__ T,
    float* __restrict__ out) {
  __shared__ float ring[RS][H_];             // 16 KB WG-private h history
  __shared__ alignas(16) float hid[H_];      // masked hidden (GRU input)
  __shared__ float hps[H_];                  // h_prev stash
  __shared__ alignas(16) float pt[H_];       // h_prev + skip_p
  __shared__ alignas(16) float xt[X_];       // x feedback (prev out row)
  __shared__ float part[4][4][H_];           // 16 KB gate partials
  __shared__ float pp[16][X_];               // 4 KB projection partials

  const int t = threadIdx.x;
  const int col = t & 255;  // h column (phase 1)
  const int kq = t >> 8;    // K quarter (phase 1)
  const int b = blockIdx.x;
  const int skip = skipp[0];
  const uint4* Thh = T;
  const uint4* Tih = T + U4_HH;
  const uint4* Tou = T + U4_HH + U4_IH;

  float bsr = 0, bsz = 0, bin_ = 0, bhn_ = 0;
  if (t < H_) {
    bsr = b_ih[t] + b_hh[t];
    bsz = b_ih[H_ + t] + b_hh[H_ + t];
    bin_ = b_ih[2 * H_ + t];
    bhn_ = b_hh[2 * H_ + t];
  }
  if (t < X_) xt[t] = 0.f;  // GO token
  if (t < H_) {
    float hp = h_enc[(size_t)b * H_ + t];
    Tab t0 = tables(0, skip, mask0, mask1);
    hps[t] = hp;
    hid[t] = t0.m0 * hp;  // skip_g at i=0 is always zero
  }
  __syncthreads();

  for (int i = 0; i < T_; ++i) {
    // ---- phase 1: gate partials, K split 4 ways (all 1024 threads) ----
    {
      float ar = 0, az = 0, ani = 0, anh = 0;
      const float4* h4 = (const float4*)hid;
      const uint4* wh = Thh + (size_t)(kq * 8) * 768 + col;
#pragma unroll
      for (int j8 = 0; j8 < 8; ++j8) {
        uint4 wr = wh[0], wz = wh[256], wn = wh[512];
        float4 ha = h4[kq * 16 + j8 * 2];
        float4 hb = h4[kq * 16 + j8 * 2 + 1];
        ar = dot8(wr, ha, hb, ar);
        az = dot8(wz, ha, hb, az);
        anh = dot8(wn, ha, hb, anh);
        wh += 768;
      }
      const float4* x4 = (const float4*)xt;
      const uint4* wi = Tih + (size_t)(kq * 2) * 768 + col;
#pragma unroll
      for (int j8 = 0; j8 < 2; ++j8) {
        uint4 wr = wi[0], wz = wi[256], wn = wi[512];
        float4 xa = x4[kq * 4 + j8 * 2];
        float4 xb = x4[kq * 4 + j8 * 2 + 1];
        ar = dot8(wr, xa, xb, ar);
        az = dot8(wz, xa, xb, az);
        ani = dot8(wn, xa, xb, ani);
        wi += 768;
      }
      part[kq][0][col] = ar;
      part[kq][1][col] = az;
      part[kq][2][col] = ani;
      part[kq][3][col] = anh;
    }
    __syncthreads();

    // ---- phase 2: finalize gates + build next step's hidden (t<256) ----
    if (t < H_) {
      Tab tb = tables(i, skip, mask0, mask1);
      float sr = part[0][0][t] + part[1][0][t] + part[2][0][t] + part[3][0][t];
      float sz = part[0][1][t] + part[1][1][t] + part[2][1][t] + part[3][1][t];
      float sni = part[0][2][t] + part[1][2][t] + part[2][2][t] + part[3][2][t];
      float snh = part[0][3][t] + part[1][3][t] + part[2][3][t] + part[3][3][t];
      float r = sigmoid_f(sr + bsr);
      float z = sigmoid_f(sz + bsz);
      float n = tanh_f((sni + bin_) + r * (snh + bhn_));
      float hv = hid[t];
      float hn = fmaf(z, hv - n, n);  // (1-z)*n + z*hidden
      ring[i & (RS - 1)][t] = hn;
      float sp = tb.pz ? 0.f
                       : ((tb.pi == i) ? hn : ring[tb.pi & (RS - 1)][t]);
      pt[t] = hps[t] + sp;
      if (i + 1 < T_) {
        Tab tn = tables(i + 1, skip, mask0, mask1);
        float sgn = tn.gz ? 0.f : ring[tn.gi & (RS - 1)][t];  // same-thread RAW ok
        hid[t] = tn.m0 * hn + tn.m1 * sgn;
        hps[t] = hn;
      }
    }
    __syncthreads();

    // ---- phase 3: projection partials, K split 16 ways (all threads) ----
    {
      int xcol = t & 63, k16 = t >> 6;
      const float4* p4 = (const float4*)pt;
      const uint4* wo = Tou + (size_t)(k16 * 2) * 64 + xcol;
      float acc = dot8(wo[0], p4[k16 * 4], p4[k16 * 4 + 1], 0.f);
      acc = dot8(wo[64], p4[k16 * 4 + 2], p4[k16 * 4 + 3], acc);
      pp[k16][xcol] = acc;
    }
    __syncthreads();

    // ---- phase 4: finalize out + feedback (t<64) ----
    if (t < X_) {
      float o = b_out[t];
#pragma unroll
      for (int j = 0; j < 16; ++j) o += pp[j][t];
      out[(size_t)b * T_ * X_ + (size_t)i * X_ + t] = o;
      xt[t] = o;
    }
    __syncthreads();
  }
}

extern "C" void kernel_launch(void* const* d_in, const int* in_sizes, int n_in,
                              void* d_out, int out_size, void* d_ws,
                              size_t ws_size, hipStream_t stream) {
  (void)in_sizes; (void)n_in; (void)out_size; (void)ws_size;
  // d_in[0] = input [B,T,X] — unused by the reference computation.
  const float* h_enc = (const float*)d_in[1];
  const float* W_ih = (const float*)d_in[2];
  const float* W_hh = (const float*)d_in[3];
  const float* b_ih = (const float*)d_in[4];
  const float* b_hh = (const float*)d_in[5];
  const float* W_out = (const float*)d_in[6];
  const float* b_out = (const float*)d_in[7];
  const int* mask0 = (const int*)d_in[8];
  const int* mask1 = (const int*)d_in[9];
  const int* skipp = (const int*)d_in[10];
  float* out = (float*)d_out;
  uint4* T = (uint4*)d_ws;  // 512 KB bf16 transposed weights

  prep_kernel<<<dim3(U4_TOTAL / 256), dim3(256), 0, stream>>>(W_ih, W_hh,
                                                              W_out, T);
  // 45056 B dynamic LDS pushes total >80 KB: guarantees 1 WG/CU (two WGs
  // sharing a CU would double the per-CU L2 weight stream).
  decoder_kernel<<<dim3(NWG), dim3(NT), 45056, stream>>>(
      h_enc, b_ih, b_hh, b_out, mask0, mask1, skipp, T, out);
}

// Round 6
// 1699.439 us; speedup vs baseline: 18.9757x; 18.9757x over previous
//
#include <hip/hip_runtime.h>

// Decoder GRU, B=128 T=512 X=64 H=256, skip=4 (runtime).
// Round 6: persistent-RNN.  R5 showed any per-step weight re-stream through
// L2 is fragile (27.5 GB fabric traffic when it thrashes).  Here weights live
// in REGISTERS as fp16 for the whole T-loop: 128 WGs x 512 thr, 1 batch/WG,
// thread (c = h-col, kh = k-half) holds W_hh[3][c][128k] + W_ih[3][c][32k]
// packed 2-per-VGPR (~120 weight regs).  W_out fp16 in LDS.  Activations as
// packed-fp16 pairs in LDS, v_dot2_f32_f16 (fp32 accum).  Per-step memory
// traffic: 256 B out-write.  All recurrent state in LDS/regs, zero inter-WG
// communication.  LDS padded to ~93 KB -> hard 1 WG/CU.
typedef _Float16 h2_t __attribute__((ext_vector_type(2)));

constexpr int T_ = 512;
constexpr int X_ = 64;
constexpr int H_ = 256;
constexpr int NWG = 128;  // 1 batch per WG
constexpr int NT = 512;   // 8 waves (2/SIMD at 1 WG/CU)
constexpr int RS = 16;    // ring slots; lookback 2*skip, OK for skip <= 7

// fp16 weight images in d_ws (uint4 units)
constexpr int GHH_U4 = 3 * 2 * 16 * 256;  // 24576 (384 KB) [g][kh][j][c]
constexpr int GIH_U4 = 3 * 2 * 4 * 256;   //  6144 ( 96 KB) [g][kh][j][c]
constexpr int GOUT_U4 = 2048;             //        ( 32 KB) [q][xc-pair]
constexpr int G_TOTAL = GHH_U4 + GIH_U4 + GOUT_U4;  // 32768 uint4 = 512 KB

__device__ __forceinline__ float sigmoid_f(float x) {
  float e = __expf(fminf(-x, 80.f));
  return 1.f / (1.f + e);
}
__device__ __forceinline__ float tanh_f(float x) {
  float e = __expf(fminf(-2.f * x, 80.f));
  return (1.f - e) / (1.f + e);
}

__device__ __forceinline__ unsigned pk2(float a, float b) {
  h2_t v;
  v[0] = (_Float16)a;
  v[1] = (_Float16)b;
  return __builtin_bit_cast(unsigned, v);
}
__device__ __forceinline__ uint2 pk4(const float* s) {
  return make_uint2(pk2(s[0], s[1]), pk2(s[2], s[3]));
}
__device__ __forceinline__ uint4 pk8(const float* s) {
  return make_uint4(pk2(s[0], s[1]), pk2(s[2], s[3]), pk2(s[4], s[5]),
                    pk2(s[6], s[7]));
}

// fp16-pair dot with fp32 accumulate (v_dot2_f32_f16; fallback v_fma_mix)
__device__ __forceinline__ float dotp(unsigned w, unsigned h, float acc) {
  h2_t wv = __builtin_bit_cast(h2_t, w);
  h2_t hv = __builtin_bit_cast(h2_t, h);
#if __has_builtin(__builtin_amdgcn_fdot2)
  return __builtin_amdgcn_fdot2(wv, hv, acc, false);
#else
  acc = fmaf((float)wv[0], (float)hv[0], acc);
  return fmaf((float)wv[1], (float)hv[1], acc);
#endif
}
__device__ __forceinline__ float dotq(uint4 w, uint4 h, float acc) {
  acc = dotp(w.x, h.x, acc);
  acc = dotp(w.y, h.y, acc);
  acc = dotp(w.z, h.z, acc);
  acc = dotp(w.w, h.w, acc);
  return acc;
}

// One-time fp32 -> fp16 pack + transpose into register/LDS-friendly layouts.
__global__ void prep_kernel(const float* __restrict__ Wih,
                            const float* __restrict__ Whh,
                            const float* __restrict__ Wout,
                            uint4* __restrict__ G) {
  int id = blockIdx.x * 256 + threadIdx.x;
  if (id < GHH_U4) {
    int c = id & 255, r = id >> 8;
    int j = r & 15, gk = r >> 4, g = gk >> 1, kh = gk & 1;
    G[id] = pk8(Whh + (size_t)(g * 256 + c) * H_ + kh * 128 + j * 8);
  } else if (id < GHH_U4 + GIH_U4) {
    int jd = id - GHH_U4;
    int c = jd & 255, r = jd >> 8;
    int j = r & 3, gk = r >> 2, g = gk >> 1, kh = gk & 1;
    G[id] = pk8(Wih + (size_t)(g * 256 + c) * X_ + kh * 32 + j * 8);
  } else if (id < G_TOTAL) {
    int jd = id - GHH_U4 - GIH_U4;
    int q = jd >> 5, xcp = (jd & 31) * 2;  // k-quad q, x-col pair
    uint2 a = pk4(Wout + (size_t)xcp * H_ + q * 4);
    uint2 b2 = pk4(Wout + (size_t)(xcp + 1) * H_ + q * 4);
    G[id] = make_uint4(a.x, a.y, b2.x, b2.y);
  }
}

__global__ __launch_bounds__(NT, 1) void decoder_kernel(
    const float* __restrict__ h_enc, const float* __restrict__ b_ih,
    const float* __restrict__ b_hh, const float* __restrict__ b_out,
    const int* __restrict__ mask0, const int* __restrict__ mask1,
    const int* __restrict__ skipp, const uint4* __restrict__ G,
    float* __restrict__ out) {
  __shared__ float ring[RS][H_];              // 16 KB h history
  __shared__ float part[2][4][H_];            // 8 KB gate partials
  __shared__ alignas(16) uint2 wout_l[64 * 64];  // 32 KB W_out fp16 [q][xc]
  __shared__ alignas(16) unsigned hid2[H_ / 2];  // hidden, fp16 pairs
  __shared__ alignas(16) unsigned pt2[H_ / 2];   // h_prev+skip_p, fp16 pairs
  __shared__ alignas(16) unsigned xt2[X_ / 2];   // x feedback, fp16 pairs
  __shared__ float pp[8][X_];                 // 2 KB projection partials
  __shared__ float lds_pad[8192];             // 32 KB: forces 1 WG/CU

  const int t = threadIdx.x;
  const int b = blockIdx.x;
  const int c = t & 255, kh = t >> 8;
  ((volatile float*)lds_pad)[t] = 0.f;  // keep pad allocated

  // ---- persistent weight registers (fp16 pairs) ----
  uint4 whh[48];  // 3 gates x 16 uint4 (128 k each)
  uint4 wih[12];  // 3 gates x 4 uint4 (32 k each)
#pragma unroll
  for (int u = 0; u < 48; ++u)
    whh[u] = G[((u >> 4) * 32 + kh * 16 + (u & 15)) * 256 + c];
#pragma unroll
  for (int u = 0; u < 12; ++u)
    whh[0] = whh[0],  // no-op to keep formatting sane
    wih[u] = G[GHH_U4 + (((u >> 2) * 8 + kh * 4 + (u & 3)) * 256 + c)];
  {
    uint4* wl = (uint4*)wout_l;
    const uint4* Go = G + GHH_U4 + GIH_U4;
#pragma unroll
    for (int j = 0; j < 4; ++j) wl[t + NT * j] = Go[t + NT * j];
  }

  const int skip = skipp[0];
  float bsr = 0, bsz = 0, bin_ = 0, bhn_ = 0, hid_reg = 0, hps_reg = 0;
  if (t < H_) {
    bsr = b_ih[t] + b_hh[t];
    bsz = b_ih[H_ + t] + b_hh[H_ + t];
    bin_ = b_ih[2 * H_ + t];
    bhn_ = b_hh[2 * H_ + t];
    float hp = h_enc[(size_t)b * H_ + t];
    hid_reg = (float)mask0[0] * hp;  // skip_g at i=0 is always zero
    hps_reg = hp;
    float ho = __shfl_xor(hid_reg, 1);
    if (!(t & 1)) hid2[t >> 1] = pk2(hid_reg, ho);
  }
  if (t < X_ / 2) xt2[t] = 0u;  // GO token
  __syncthreads();

  for (int i = 0; i < T_; ++i) {
    // ---- P1: gate partials (all 512 thr; k-half per thread) ----
    float ar = 0, az = 0, anh = 0, ani = 0;
    {
      const uint4* h4 = ((const uint4*)hid2) + kh * 16;
#pragma unroll
      for (int j = 0; j < 16; ++j) {
        uint4 h8 = h4[j];  // broadcast (wave-uniform address)
        ar = dotq(whh[j], h8, ar);
        az = dotq(whh[16 + j], h8, az);
        anh = dotq(whh[32 + j], h8, anh);
      }
      const uint4* x4 = ((const uint4*)xt2) + kh * 4;
#pragma unroll
      for (int j = 0; j < 4; ++j) {
        uint4 x8 = x4[j];
        ar = dotq(wih[j], x8, ar);
        az = dotq(wih[4 + j], x8, az);
        ani = dotq(wih[8 + j], x8, ani);
      }
    }
    part[kh][0][c] = ar;
    part[kh][1][c] = az;
    part[kh][2][c] = ani;
    part[kh][3][c] = anh;
    __syncthreads();

    // ---- P2: finalize gates, h_new, next hidden, proj input (t<256) ----
    if (t < H_) {
      float sr = part[0][0][t] + part[1][0][t] + bsr;
      float sz = part[0][1][t] + part[1][1][t] + bsz;
      float sni = part[0][2][t] + part[1][2][t] + bin_;
      float snh = part[0][3][t] + part[1][3][t] + bhn_;
      float r = sigmoid_f(sr);
      float z = sigmoid_f(sz);
      float n = tanh_f(sni + r * snh);
      float hn = fmaf(z, hid_reg - n, n);  // (1-z)*n + z*hidden
      ring[i & (RS - 1)][t] = hn;
      int ppos = (i < skip) ? 2 * i + 1 : i - skip;
      bool pz = ppos < skip;
      int pi = ppos - skip;
      if (pi < 0) pi = 0;
      float sp = pz ? 0.f : ((pi == i) ? hn : ring[pi & (RS - 1)][t]);
      float ptv = hps_reg + sp;
      float hidn = 0.f;
      if (i + 1 < T_) {
        int i1 = i + 1;
        float m0 = (float)mask0[i1], m1 = (float)mask1[i1];
        int pg = (i1 < skip) ? 2 * i1 : i1 - skip;
        bool gz = pg < skip;
        int gi = pg - skip;
        if (gi < 0) gi = 0;
        if (gi >= i1) gz = true;  // unwritten slot == reference zero init
        float sg = gz ? 0.f : ring[gi & (RS - 1)][t];
        hidn = m0 * hn + m1 * sg;
      }
      hps_reg = hn;
      hid_reg = hidn;
      float ho = __shfl_xor(hidn, 1);
      float po = __shfl_xor(ptv, 1);
      if (!(t & 1)) {
        hid2[t >> 1] = pk2(hidn, ho);
        pt2[t >> 1] = pk2(ptv, po);
      }
    }
    __syncthreads();

    // ---- P3: projection partials (all 512 thr; 32-k slice each) ----
    {
      int xc = t & 63, k8 = t >> 6;
      const uint4* p4 = ((const uint4*)pt2) + k8 * 4;
      const uint2* w = wout_l + k8 * 8 * 64 + xc;
      float acc = 0.f;
#pragma unroll
      for (int j = 0; j < 4; ++j) {
        uint4 pv = p4[j];  // broadcast
        uint2 wa = w[(2 * j) * 64];
        uint2 wb = w[(2 * j + 1) * 64];
        acc = dotp(wa.x, pv.x, acc);
        acc = dotp(wa.y, pv.y, acc);
        acc = dotp(wb.x, pv.z, acc);
        acc = dotp(wb.y, pv.w, acc);
      }
      pp[k8][xc] = acc;
    }
    __syncthreads();

    // ---- P4: finalize out + x feedback (t<64, one wave) ----
    if (t < X_) {
      float o = b_out[t];
#pragma unroll
      for (int j = 0; j < 8; ++j) o += pp[j][t];
      out[(size_t)b * T_ * X_ + (size_t)i * X_ + t] = o;
      float oo = __shfl_xor(o, 1);
      if (!(t & 1)) xt2[t >> 1] = pk2(o, oo);
    }
    __syncthreads();
  }
}

extern "C" void kernel_launch(void* const* d_in, const int* in_sizes, int n_in,
                              void* d_out, int out_size, void* d_ws,
                              size_t ws_size, hipStream_t stream) {
  (void)in_sizes; (void)n_in; (void)out_size; (void)ws_size;
  // d_in[0] = input [B,T,X] — unused by the reference computation.
  const float* h_enc = (const float*)d_in[1];
  const float* W_ih = (const float*)d_in[2];
  const float* W_hh = (const float*)d_in[3];
  const float* b_ih = (const float*)d_in[4];
  const float* b_hh = (const float*)d_in[5];
  const float* W_out = (const float*)d_in[6];
  const float* b_out = (const float*)d_in[7];
  const int* mask0 = (const int*)d_in[8];
  const int* mask1 = (const int*)d_in[9];
  const int* skipp = (const int*)d_in[10];
  float* out = (float*)d_out;
  uint4* G = (uint4*)d_ws;  // 512 KB fp16 weight images

  prep_kernel<<<dim3(G_TOTAL / 256), dim3(256), 0, stream>>>(W_ih, W_hh,
                                                             W_out, G);
  decoder_kernel<<<dim3(NWG), dim3(NT), 0, stream>>>(
      h_enc, b_ih, b_hh, b_out, mask0, mask1, skipp, G, out);
}